// Round 15
// baseline (608.308 us; speedup 1.0000x reference)
//
#include <hip/hip_runtime.h>
#include <hip/hip_bf16.h>
#include <math.h>

typedef __attribute__((ext_vector_type(8))) short bf16x8;
typedef __attribute__((ext_vector_type(16))) float f32x16;

#define R_TOTAL 8
#define CIN     256
#define COUT    256
#define HH      128
#define WW      128
#define BB      4
#define MTOT    (COUT * R_TOTAL)   // 2048
#define KTAPS   9

#define ROWSZ 4160                 // X row slot: 2 s-halves x 130 cols x 16 (elems)
#define SHX   2080                 // one s-half of an X row (elems)
#define ABUF  4096                 // A tile: 2 s-halves x 128 rows x 16 (elems)
#define SHA   2048                 // one s-half of an A tile (elems)

// ---------------------------------------------------------------------------
// async global->LDS, 16B per lane (lane l lands at base + l*16).
// ---------------------------------------------------------------------------
__device__ __forceinline__ void g2l16(void* lds, const void* g) {
    __builtin_amdgcn_global_load_lds(
        (const __attribute__((address_space(1))) unsigned int*)g,
        (__attribute__((address_space(3))) unsigned int*)lds,
        16, 0, 0);
}

// ---------------------------------------------------------------------------
// x (B,C,H,W) fp32 -> xb (B,H,W,C) bf16 (+ one appended zero row).
// ---------------------------------------------------------------------------
__global__ __launch_bounds__(256)
void to_nhwc_bf16(const float* __restrict__ x, __hip_bfloat16* __restrict__ xb) {
    __shared__ __hip_bfloat16 t[32][33];
    const int b  = blockIdx.z;
    const int c0 = blockIdx.y * 32;
    const int p0 = blockIdx.x * 32;
    const int tx = threadIdx.x & 31;
    const int ty = threadIdx.x >> 5;
    const float* xp = x + (size_t)b * CIN * (HH * WW);
    #pragma unroll
    for (int j = 0; j < 4; ++j) {
        int c = ty * 4 + j;
        t[c][tx] = __float2bfloat16(xp[(size_t)(c0 + c) * (HH * WW) + p0 + tx]);
    }
    __syncthreads();
    __hip_bfloat16* op = xb + ((size_t)b * (HH * WW) + p0) * CIN + c0;
    #pragma unroll
    for (int j = 0; j < 4; ++j) {
        int p = ty * 4 + j;
        op[(size_t)p * CIN + tx] = t[tx][p];
    }
}

__global__ __launch_bounds__(256)
void zero_guard_row(__hip_bfloat16* __restrict__ xb) {
    size_t base = (size_t)BB * HH * WW * CIN;
    int i = blockIdx.x * 256 + threadIdx.x;
    xb[base + i] = __float2bfloat16(0.0f);
}

// ---------------------------------------------------------------------------
// Rotate weights (fp32 math == jax affine_grid/grid_sample, align_corners=F,
// zero pad) -> rwb[m][tap][i] bf16, m = o*8 + r.
// ---------------------------------------------------------------------------
__global__ __launch_bounds__(256)
void rotate_weights_bf16(const float* __restrict__ w, __hip_bfloat16* __restrict__ rwb) {
    const int i = threadIdx.x;
    const int m = blockIdx.x;
    const int o = m >> 3, r = m & 7;

    float ang = 6.283185307179586f * (float)r / 8.0f;
    float cs = cosf(ang), sn = sinf(ang);

    const float* wp = w + ((size_t)o * CIN + i) * 9;
    __hip_bfloat16* op = rwb + (size_t)m * (KTAPS * CIN) + i;

    #pragma unroll
    for (int ky = 0; ky < 3; ++ky) {
        #pragma unroll
        for (int kx = 0; kx < 3; ++kx) {
            float yg = (2.0f * (float)ky + 1.0f) / 3.0f - 1.0f;
            float xg = (2.0f * (float)kx + 1.0f) / 3.0f - 1.0f;
            float xsf = cs * xg - sn * yg;
            float ysf = sn * xg + cs * yg;
            float ix = ((xsf + 1.0f) * 3.0f - 1.0f) * 0.5f;
            float iy = ((ysf + 1.0f) * 3.0f - 1.0f) * 0.5f;
            float ix0f = floorf(ix), iy0f = floorf(iy);
            float wx1 = ix - ix0f,  wy1 = iy - iy0f;
            float wx0 = 1.0f - wx1, wy0 = 1.0f - wy1;
            int ix0 = (int)ix0f, iy0 = (int)iy0f;
            int ix1 = ix0 + 1,   iy1 = iy0 + 1;
            float acc = 0.0f;
            if (iy0 >= 0 && iy0 < 3 && ix0 >= 0 && ix0 < 3) acc += wp[iy0*3+ix0] * (wy0*wx0);
            if (iy0 >= 0 && iy0 < 3 && ix1 >= 0 && ix1 < 3) acc += wp[iy0*3+ix1] * (wy0*wx1);
            if (iy1 >= 0 && iy1 < 3 && ix0 >= 0 && ix0 < 3) acc += wp[iy1*3+ix0] * (wy1*wx0);
            if (iy1 >= 0 && iy1 < 3 && ix1 >= 0 && ix1 < 3) acc += wp[iy1*3+ix1] * (wy1*wx1);
            op[(ky * 3 + kx) * CIN] = __float2bfloat16(acc);
        }
    }
}

// ---------------------------------------------------------------------------
// Main MFMA conv (R13 schedule + 32x32x16 shape + contiguity LDS layout):
// 256 threads = 4 waves (2M x 2N), block tile 128M x 256N, wave 64M x 128N.
// LDS layout [s-half][col/row][lh]: for K-step s, lane (l31,lh) reads
// s*SH + col*16 + lh*8 -> each ds_read_b128 instruction covers a CONTIGUOUS
// 1024B region (32 cols x 2 halves) => bank-conflict-free by construction,
// no XOR swizzle anywhere (fixes R14's 5.7e7 conflicts).
// A: FOUR slots, slot(t)=t%4 (WAR-safe at issue distance 2).
// X: rolling 5-slot row buffer, slot(r,c) = (4c+r)%5 (R13 placement).
// Issue-early tap: stage -> counted vmcnt -> raw s_barrier -> ds_read -> MFMA.
// Per-tap issue counts identical to R13 -> NW tables unchanged.
// LDS 72.6 KB -> 2 blocks/CU; 108 arch + 128 acc <= 256 -> 2 waves/SIMD.
// ---------------------------------------------------------------------------
__global__ __launch_bounds__(256, 2)
void rotconv_mfma_kernel(const __hip_bfloat16* __restrict__ xb,
                         const __hip_bfloat16* __restrict__ rwb,
                         float* __restrict__ out) {
    const int tid  = threadIdx.x;
    const int lane = tid & 63;
    const int w    = tid >> 6;        // 0..3
    const int wm   = w >> 1;          // 0..1
    const int wn   = w & 1;           // 0..1  (owns output row y0+wn)
    const int l31  = lane & 31;
    const int lh   = lane >> 5;       // 0..1

    // bijective XCD swizzle (4096 % 8 == 0), m-major for A-panel L2 reuse
    const int bid = (blockIdx.x & 7) * 512 + (blockIdx.x >> 3);
    const int mt  = bid >> 8;         // 0..15
    const int nt  = bid & 255;        // 0..255
    const int b   = nt >> 6;          // 0..3
    const int y0  = (nt & 63) * 2;    // 0..126
    const int m0  = mt << 7;

    __shared__ __align__(16) __hip_bfloat16 xs[5 * ROWSZ];
    __shared__ __align__(16) __hip_bfloat16 As[4 * ABUF];

    // zero halo cols (colL 0 and 129) of both s-halves of all 5 slots
    for (int j = tid; j < 5 * 64; j += 256) {
        int slot = j >> 6;
        int rem  = j & 63;
        int s    = rem >> 5;
        int colsel = (rem >> 4) & 1;
        int e    = rem & 15;
        int colL = colsel ? 129 : 0;
        xs[slot * ROWSZ + s * SHX + colL * 16 + e] = __float2bfloat16(0.0f);
    }

    // ---- fragment read bases (element units, no swizzle) ----
    const int aBase = (wm * 64 + l31) * 16 + lh * 8;      // + mi*512 + s*SHA
    int bBase[3];
    #pragma unroll
    for (int kx = 0; kx < 3; ++kx)
        bBase[kx] = (l31 + kx) * 16 + lh * 8;             // + nj*512 + s*SHX

    // ---- A staging: wave w = rows 32w..32w+31; one g2l16 per s-half ----
    const int dstA = w * 512;                             // elems, + s*SHA
    const int voffA = (m0 + w * 32 + (lane >> 1)) * (KTAPS * CIN) + 8 * (lane & 1);

    // ---- X staging: wave w = global cols 32w..32w+31; 2 parts (s) per row --
    int rowOff[4];                                        // wave-uniform
    #pragma unroll
    for (int r = 0; r < 4; ++r) {
        int gy = y0 - 1 + r;
        int rowIdx = ((unsigned)gy < (unsigned)HH) ? (b * HH + gy) : (BB * HH);
        rowOff[r] = rowIdx * (WW * CIN);
    }
    const int voffX = (w * 32 + (lane >> 1)) * CIN + 8 * (lane & 1);
    const int dstX  = (1 + 32 * w) * 16;                  // elems, + s*SHX

    f32x16 acc[2][4];
    #pragma unroll
    for (int mi = 0; mi < 2; ++mi)
        #pragma unroll
        for (int ni = 0; ni < 4; ++ni)
            #pragma unroll
            for (int e = 0; e < 16; ++e)
                acc[mi][ni][e] = 0.0f;

    __syncthreads();   // halo zeros visible

    // prologue: X rows r0..r3 (both s-halves) -> slots 0..3; A(0)->s0, A(1)->s1
    #pragma unroll
    for (int r = 0; r < 4; ++r) {
        g2l16(xs + r * ROWSZ + dstX,       xb + rowOff[r] + voffX);
        g2l16(xs + r * ROWSZ + SHX + dstX, xb + rowOff[r] + voffX + 16);
    }
    g2l16(As + dstA,              rwb + voffA);
    g2l16(As + SHA + dstA,        rwb + voffA + 16);
    g2l16(As + ABUF + dstA,       rwb + voffA + CIN);
    g2l16(As + ABUF + SHA + dstA, rwb + voffA + CIN + 16);
    asm volatile("s_waitcnt vmcnt(0)" ::: "memory");
    __syncthreads();

#define WRAP5(v) ((v) >= 5 ? (v) - 5 : (v))

// ---- one tap (literal chunk C, tap P): issue A(t+2) both s-halves into slot
//      (C+P+2)&3 [+ one X part: row XIDX>>1, s-half XIDX&1] -> counted wait
//      -> barrier -> 2 K-steps of {2 A + 4 B contiguous b128, 8 mfma_32x32}.
#define TAP(C, P, NW, DOA, DOX, XIDX, XSLOT, XOFF)                             \
  {                                                                            \
    if (DOA) {                                                                 \
      __hip_bfloat16* ab = As + (((C) + (P) + 2) & 3) * ABUF;                  \
      const int aofs = (((P) + 2) % 9) * CIN + ((((P) + 2) / 9) + (C)) * 32;   \
      g2l16(ab + dstA,       rwb + voffA + aofs);                              \
      g2l16(ab + SHA + dstA, rwb + voffA + aofs + 16);                         \
    }                                                                          \
    if (DOX) {                                                                 \
      g2l16(xs + (XSLOT) * ROWSZ + (((XIDX) & 1) ? SHX : 0) + dstX,            \
            xb + rowOff[(XIDX) >> 1] + voffX + (XOFF)                          \
               + (((XIDX) & 1) ? 16 : 0));                                     \
    }                                                                          \
    asm volatile("s_waitcnt vmcnt(%0)" :: "i"(NW) : "memory");                 \
    asm volatile("s_barrier" ::: "memory");                                    \
    {                                                                          \
      const __hip_bfloat16* ar = As + (((C) + (P)) & 3) * ABUF;                \
      const __hip_bfloat16* br =                                               \
          ((P) / 3 == 0 ? xrow0 : (P) / 3 == 1 ? xrow1 : xrow2);               \
      _Pragma("unroll")                                                        \
      for (int s = 0; s < 2; ++s) {                                            \
        const __hip_bfloat16* as_ = ar + s * SHA + aBase;                      \
        const __hip_bfloat16* bs_ = br + s * SHX + bBase[(P) % 3];             \
        bf16x8 a0 = *(const bf16x8*)(as_);                                     \
        bf16x8 a1 = *(const bf16x8*)(as_ + 512);                               \
        bf16x8 b0 = *(const bf16x8*)(bs_);                                     \
        bf16x8 b1 = *(const bf16x8*)(bs_ + 512);                               \
        bf16x8 b2 = *(const bf16x8*)(bs_ + 1024);                              \
        bf16x8 b3 = *(const bf16x8*)(bs_ + 1536);                              \
        __builtin_amdgcn_s_setprio(1);                                         \
        acc[0][0] = __builtin_amdgcn_mfma_f32_32x32x16_bf16(a0, b0, acc[0][0], 0, 0, 0); \
        acc[0][1] = __builtin_amdgcn_mfma_f32_32x32x16_bf16(a0, b1, acc[0][1], 0, 0, 0); \
        acc[0][2] = __builtin_amdgcn_mfma_f32_32x32x16_bf16(a0, b2, acc[0][2], 0, 0, 0); \
        acc[0][3] = __builtin_amdgcn_mfma_f32_32x32x16_bf16(a0, b3, acc[0][3], 0, 0, 0); \
        acc[1][0] = __builtin_amdgcn_mfma_f32_32x32x16_bf16(a1, b0, acc[1][0], 0, 0, 0); \
        acc[1][1] = __builtin_amdgcn_mfma_f32_32x32x16_bf16(a1, b1, acc[1][1], 0, 0, 0); \
        acc[1][2] = __builtin_amdgcn_mfma_f32_32x32x16_bf16(a1, b2, acc[1][2], 0, 0, 0); \
        acc[1][3] = __builtin_amdgcn_mfma_f32_32x32x16_bf16(a1, b3, acc[1][3], 0, 0, 0); \
        __builtin_amdgcn_s_setprio(0);                                         \
      }                                                                        \
    }                                                                          \
  }

#define CHUNK_HDR(C)                                                           \
    const int rbw = ((4 * (C)) % 5) + wn;                                      \
    const __hip_bfloat16* xrow0 = xs + WRAP5(rbw) * ROWSZ;                     \
    const __hip_bfloat16* xrow1 = xs + WRAP5(rbw + 1) * ROWSZ;                 \
    const __hip_bfloat16* xrow2 = xs + WRAP5(rbw + 2) * ROWSZ;

// steady chunk C=1..6: X row3@C (2 s-parts) at taps 1-2 (slot (4C+3)%5),
// rows 0-2 of C+1 at taps 3-8. NW [6,6,6,7,7,7,7,7,7].
#define CHK_MID(C)                                                             \
  { CHUNK_HDR(C)                                                               \
    TAP(C, 0, 6, 1, 0, 0, 0, 0)                                                \
    TAP(C, 1, 6, 1, 1, 6, (4*(C)+3)%5, (C)*32)                                 \
    TAP(C, 2, 6, 1, 1, 7, (4*(C)+3)%5, (C)*32)                                 \
    TAP(C, 3, 7, 1, 1, 0, (4*(C)+4)%5, ((C)+1)*32)                             \
    TAP(C, 4, 7, 1, 1, 1, (4*(C)+4)%5, ((C)+1)*32)                             \
    TAP(C, 5, 7, 1, 1, 2, (4*(C))%5,   ((C)+1)*32)                             \
    TAP(C, 6, 7, 1, 1, 3, (4*(C))%5,   ((C)+1)*32)                             \
    TAP(C, 7, 7, 1, 1, 4, (4*(C)+1)%5, ((C)+1)*32)                             \
    TAP(C, 8, 7, 1, 1, 5, (4*(C)+1)%5, ((C)+1)*32)                             \
  }

    // ---- chunk 0: rows 0-3 prologue-staged; stage rows 0-2 of c1 at taps 3-8
    { CHUNK_HDR(0)
      TAP(0, 0, 2, 1, 0, 0, 0, 0)
      TAP(0, 1, 4, 1, 0, 0, 0, 0)
      TAP(0, 2, 4, 1, 0, 0, 0, 0)
      TAP(0, 3, 5, 1, 1, 0, 4, 32)
      TAP(0, 4, 6, 1, 1, 1, 4, 32)
      TAP(0, 5, 7, 1, 1, 2, 0, 32)
      TAP(0, 6, 7, 1, 1, 3, 0, 32)
      TAP(0, 7, 7, 1, 1, 4, 1, 32)
      TAP(0, 8, 7, 1, 1, 5, 1, 32)
    }

    CHK_MID(1) CHK_MID(2) CHK_MID(3) CHK_MID(4) CHK_MID(5) CHK_MID(6)

    // ---- tail chunk 7: row3@c7 at taps 1-2 (slot (31)%5=1); A while t+2<=71
    { CHUNK_HDR(7)
      TAP(7, 0, 6, 1, 0, 0, 0, 0)
      TAP(7, 1, 6, 1, 1, 6, 1, 224)
      TAP(7, 2, 6, 1, 1, 7, 1, 224)
      TAP(7, 3, 6, 1, 0, 0, 0, 0)
      TAP(7, 4, 5, 1, 0, 0, 0, 0)
      TAP(7, 5, 4, 1, 0, 0, 0, 0)
      TAP(7, 6, 4, 1, 0, 0, 0, 0)
      TAP(7, 7, 2, 0, 0, 0, 0, 0)
      TAP(7, 8, 0, 0, 0, 0, 0, 0)
    }

#undef TAP
#undef CHK_MID
#undef CHUNK_HDR
#undef WRAP5

    // epilogue: 32x32 C/D layout col=lane&31, row=(reg&3)+8*(reg>>2)+4*lh.
    // r = (reg&3) | (lh<<2); o-offset g = reg>>2. max over reg&3 then
    // shfl_xor(32); lanes<32 store. (Verified correct in R14.)
    const int yOut = y0 + wn;
    #pragma unroll
    for (int mi = 0; mi < 2; ++mi) {
        #pragma unroll
        for (int ni = 0; ni < 4; ++ni) {
            #pragma unroll
            for (int g = 0; g < 4; ++g) {
                float v = fmaxf(fmaxf(acc[mi][ni][4*g+0], acc[mi][ni][4*g+1]),
                                fmaxf(acc[mi][ni][4*g+2], acc[mi][ni][4*g+3]));
                v = fmaxf(v, __shfl_xor(v, 32));
                if (lane < 32) {
                    int o = ((m0 + wm * 64 + mi * 32) >> 3) + g;
                    out[(((size_t)(b * COUT + o)) * HH + yOut) * WW
                        + ni * 32 + lane] = v;
                }
            }
        }
    }
}

// ===========================================================================
// Fallback fp32 path (round-0, known-correct) in case ws is too small.
// ===========================================================================
__global__ void rotate_weights_kernel(const float* __restrict__ w,
                                      float* __restrict__ rw,
                                      int r0, int rcount) {
    int idx = blockIdx.x * blockDim.x + threadIdx.x;
    int total = COUT * CIN * rcount;
    if (idx >= total) return;
    int rr = idx % rcount;
    int ii = (idx / rcount) % CIN;
    int oo = idx / (rcount * CIN);
    int r  = r0 + rr;
    float ang = 6.283185307179586f * (float)r / 8.0f;
    float cs = cosf(ang), sn = sinf(ang);
    const float* wp = w  + ((size_t)oo * CIN + ii) * 9;
    float*       op = rw + (((size_t)oo * CIN + ii) * rcount + rr) * 9;
    #pragma unroll
    for (int ky = 0; ky < 3; ++ky)
        #pragma unroll
        for (int kx = 0; kx < 3; ++kx) {
            float yg = (2.0f * ky + 1.0f) / 3.0f - 1.0f;
            float xg = (2.0f * kx + 1.0f) / 3.0f - 1.0f;
            float xsf = cs * xg - sn * yg;
            float ysf = sn * xg + cs * yg;
            float ix = ((xsf + 1.0f) * 3.0f - 1.0f) * 0.5f;
            float iy = ((ysf + 1.0f) * 3.0f - 1.0f) * 0.5f;
            float ix0f = floorf(ix), iy0f = floorf(iy);
            float wx1 = ix - ix0f,  wy1 = iy - iy0f;
            float wx0 = 1.0f - wx1, wy0 = 1.0f - wy1;
            int ix0 = (int)ix0f, iy0 = (int)iy0f;
            int ix1 = ix0 + 1,   iy1 = iy0 + 1;
            float acc = 0.0f;
            if (iy0 >= 0 && iy0 < 3 && ix0 >= 0 && ix0 < 3) acc += wp[iy0*3+ix0]*(wy0*wx0);
            if (iy0 >= 0 && iy0 < 3 && ix1 >= 0 && ix1 < 3) acc += wp[iy0*3+ix1]*(wy0*wx1);
            if (iy1 >= 0 && iy1 < 3 && ix0 >= 0 && ix0 < 3) acc += wp[iy1*3+ix0]*(wy1*wx0);
            if (iy1 >= 0 && iy1 < 3 && ix1 >= 0 && ix1 < 3) acc += wp[iy1*3+ix1]*(wy1*wx1);
            op[ky * 3 + kx] = acc;
        }
}

template <int RCOUNT>
__global__ __launch_bounds__(256)
void rotconv_max_kernel(const float* __restrict__ x,
                        const float* __restrict__ rw,
                        float* __restrict__ out,
                        int first) {
    const int tid = threadIdx.x;
    const int tx = tid & 15;
    const int ty = tid >> 4;
    const int x0 = blockIdx.x * 32;
    const int y0 = blockIdx.y * 32;
    const int o  = blockIdx.z % COUT;
    const int b  = blockIdx.z / COUT;
    __shared__ float xsm[34][36];
    float acc[RCOUNT][2][2];
    #pragma unroll
    for (int r = 0; r < RCOUNT; ++r)
        #pragma unroll
        for (int py = 0; py < 2; ++py)
            #pragma unroll
            for (int px = 0; px < 2; ++px) acc[r][py][px] = 0.0f;
    for (int i = 0; i < CIN; ++i) {
        __syncthreads();
        const float* xp = x + ((size_t)(b * CIN + i)) * (HH * WW);
        for (int idx = tid; idx < 34 * 34; idx += 256) {
            int row = idx / 34, col = idx - row * 34;
            int gy = y0 - 1 + row, gx = x0 - 1 + col;
            float v = 0.0f;
            if (gy >= 0 && gy < HH && gx >= 0 && gx < WW) v = xp[gy * WW + gx];
            xsm[row][col] = v;
        }
        __syncthreads();
        float xv[4][4];
        #pragma unroll
        for (int ry = 0; ry < 4; ++ry)
            #pragma unroll
            for (int cx = 0; cx < 4; ++cx) xv[ry][cx] = xsm[ty*2+ry][tx*2+cx];
        const float* wp = rw + ((size_t)(o * CIN + i)) * (RCOUNT * 9);
        #pragma unroll
        for (int r = 0; r < RCOUNT; ++r) {
            float wv[9];
            #pragma unroll
            for (int t2 = 0; t2 < 9; ++t2) wv[t2] = wp[r * 9 + t2];
            #pragma unroll
            for (int py = 0; py < 2; ++py)
                #pragma unroll
                for (int px = 0; px < 2; ++px) {
                    float a = acc[r][py][px];
                    #pragma unroll
                    for (int ky = 0; ky < 3; ++ky)
                        #pragma unroll
                        for (int kx = 0; kx < 3; ++kx)
                            a += xv[py+ky][px+kx] * wv[ky*3+kx];
                    acc[r][py][px] = a;
                }
        }
    }
    #pragma unroll
    for (int py = 0; py < 2; ++py)
        #pragma unroll
        for (int px = 0; px < 2; ++px) {
            float m = acc[0][py][px];
            #pragma unroll
            for (int r = 1; r < RCOUNT; ++r) m = fmaxf(m, acc[r][py][px]);
            int oy = y0 + ty * 2 + py;
            int ox = x0 + tx * 2 + px;
            float* op = out + (((size_t)(b * COUT + o)) * HH + oy) * WW + ox;
            if (first) *op = m;
            else       *op = fmaxf(*op, m);
        }
}

// ===========================================================================
extern "C" void kernel_launch(void* const* d_in, const int* in_sizes, int n_in,
                              void* d_out, int out_size, void* d_ws, size_t ws_size,
                              hipStream_t stream) {
    const float* x = (const float*)d_in[0];
    const float* w = (const float*)d_in[1];
    float* out = (float*)d_out;

    const size_t xbBytes = ((size_t)BB * HH * WW + WW) * CIN * sizeof(__hip_bfloat16); // +1 zero row
    const size_t rwBytes = (size_t)MTOT * KTAPS * CIN * sizeof(__hip_bfloat16);

    if (ws_size >= xbBytes + rwBytes) {
        __hip_bfloat16* xbuf = (__hip_bfloat16*)d_ws;
        __hip_bfloat16* rwb  = (__hip_bfloat16*)((char*)d_ws + xbBytes);

        to_nhwc_bf16<<<dim3((HH * WW) / 32, CIN / 32, BB), 256, 0, stream>>>(x, xbuf);
        zero_guard_row<<<(WW * CIN) / 256, 256, 0, stream>>>(xbuf);
        rotate_weights_bf16<<<MTOT, 256, 0, stream>>>(w, rwb);
        rotconv_mfma_kernel<<<4096, 256, 0, stream>>>(xbuf, rwb, out);
        return;
    }

    // ---- fallback fp32 path ----
    float* rw = (float*)d_ws;
    int chunk = 8;
    while (chunk > 1 && (size_t)COUT * CIN * chunk * 9 * sizeof(float) > ws_size)
        chunk >>= 1;
    int first = 1;
    for (int r0 = 0; r0 < R_TOTAL; r0 += chunk) {
        int rc = chunk;
        int total = COUT * CIN * rc;
        rotate_weights_kernel<<<(total + 255) / 256, 256, 0, stream>>>(w, rw, r0, rc);
        dim3 grid(WW / 32, HH / 32, BB * COUT);
        switch (rc) {
            case 8: rotconv_max_kernel<8><<<grid, 256, 0, stream>>>(x, rw, out, first); break;
            case 4: rotconv_max_kernel<4><<<grid, 256, 0, stream>>>(x, rw, out, first); break;
            case 2: rotconv_max_kernel<2><<<grid, 256, 0, stream>>>(x, rw, out, first); break;
            default: rotconv_max_kernel<1><<<grid, 256, 0, stream>>>(x, rw, out, first); break;
        }
        first = 0;
    }
}

// Round 16
// 509.974 us; speedup vs baseline: 1.1928x; 1.1928x over previous
//
#include <hip/hip_runtime.h>
#include <hip/hip_bf16.h>
#include <math.h>

typedef __attribute__((ext_vector_type(8))) short bf16x8;
typedef __attribute__((ext_vector_type(4))) float f32x4;

#define R_TOTAL 8
#define CIN     256
#define COUT    256
#define HH      128
#define WW      128
#define BB      4
#define MTOT    (COUT * R_TOTAL)   // 2048
#define KTAPS   9

#define ROWSZ 4160                 // one X row slot: 130 cols x 32 ch (elems)
#define ABUF  (128 * 32)           // 4096 elems per A buffer (8 KB)

// ---------------------------------------------------------------------------
// async global->LDS, 16B per lane (lane l lands at base + l*16).
// ---------------------------------------------------------------------------
__device__ __forceinline__ void g2l16(void* lds, const void* g) {
    __builtin_amdgcn_global_load_lds(
        (const __attribute__((address_space(1))) unsigned int*)g,
        (__attribute__((address_space(3))) unsigned int*)lds,
        16, 0, 0);
}

// ---------------------------------------------------------------------------
// x (B,C,H,W) fp32 -> xb (B,H,W,C) bf16 (+ one appended zero row).
// ---------------------------------------------------------------------------
__global__ __launch_bounds__(256)
void to_nhwc_bf16(const float* __restrict__ x, __hip_bfloat16* __restrict__ xb) {
    __shared__ __hip_bfloat16 t[32][33];
    const int b  = blockIdx.z;
    const int c0 = blockIdx.y * 32;
    const int p0 = blockIdx.x * 32;
    const int tx = threadIdx.x & 31;
    const int ty = threadIdx.x >> 5;
    const float* xp = x + (size_t)b * CIN * (HH * WW);
    #pragma unroll
    for (int j = 0; j < 4; ++j) {
        int c = ty * 4 + j;
        t[c][tx] = __float2bfloat16(xp[(size_t)(c0 + c) * (HH * WW) + p0 + tx]);
    }
    __syncthreads();
    __hip_bfloat16* op = xb + ((size_t)b * (HH * WW) + p0) * CIN + c0;
    #pragma unroll
    for (int j = 0; j < 4; ++j) {
        int p = ty * 4 + j;
        op[(size_t)p * CIN + tx] = t[tx][p];
    }
}

__global__ __launch_bounds__(256)
void zero_guard_row(__hip_bfloat16* __restrict__ xb) {
    size_t base = (size_t)BB * HH * WW * CIN;
    int i = blockIdx.x * 256 + threadIdx.x;
    xb[base + i] = __float2bfloat16(0.0f);
}

// ---------------------------------------------------------------------------
// Rotate weights (fp32 math == jax affine_grid/grid_sample, align_corners=F,
// zero pad) -> rwb[m][tap][i] bf16, m = o*8 + r.
// ---------------------------------------------------------------------------
__global__ __launch_bounds__(256)
void rotate_weights_bf16(const float* __restrict__ w, __hip_bfloat16* __restrict__ rwb) {
    const int i = threadIdx.x;
    const int m = blockIdx.x;
    const int o = m >> 3, r = m & 7;

    float ang = 6.283185307179586f * (float)r / 8.0f;
    float cs = cosf(ang), sn = sinf(ang);

    const float* wp = w + ((size_t)o * CIN + i) * 9;
    __hip_bfloat16* op = rwb + (size_t)m * (KTAPS * CIN) + i;

    #pragma unroll
    for (int ky = 0; ky < 3; ++ky) {
        #pragma unroll
        for (int kx = 0; kx < 3; ++kx) {
            float yg = (2.0f * (float)ky + 1.0f) / 3.0f - 1.0f;
            float xg = (2.0f * (float)kx + 1.0f) / 3.0f - 1.0f;
            float xsf = cs * xg - sn * yg;
            float ysf = sn * xg + cs * yg;
            float ix = ((xsf + 1.0f) * 3.0f - 1.0f) * 0.5f;
            float iy = ((ysf + 1.0f) * 3.0f - 1.0f) * 0.5f;
            float ix0f = floorf(ix), iy0f = floorf(iy);
            float wx1 = ix - ix0f,  wy1 = iy - iy0f;
            float wx0 = 1.0f - wx1, wy0 = 1.0f - wy1;
            int ix0 = (int)ix0f, iy0 = (int)iy0f;
            int ix1 = ix0 + 1,   iy1 = iy0 + 1;
            float acc = 0.0f;
            if (iy0 >= 0 && iy0 < 3 && ix0 >= 0 && ix0 < 3) acc += wp[iy0*3+ix0] * (wy0*wx0);
            if (iy0 >= 0 && iy0 < 3 && ix1 >= 0 && ix1 < 3) acc += wp[iy0*3+ix1] * (wy0*wx1);
            if (iy1 >= 0 && iy1 < 3 && ix0 >= 0 && ix0 < 3) acc += wp[iy1*3+ix0] * (wy1*wx0);
            if (iy1 >= 0 && iy1 < 3 && ix1 >= 0 && ix1 < 3) acc += wp[iy1*3+ix1] * (wy1*wx1);
            op[(ky * 3 + kx) * CIN] = __float2bfloat16(acc);
        }
    }
}

// ---------------------------------------------------------------------------
// Main MFMA conv (R13, verified 490 us / MfmaUtil 61% / 0 bank conflicts):
// 256 threads = 4 waves (2M x 2N), block tile 128M x 256N (two image rows;
// wave tile 64M x 128N -> 42.7 FLOP/LDS-byte). K = 8 chunks(32ch) x 9 taps.
// Issue-early tap: stage A(t+2) [+ one X row part] -> counted vmcnt -> raw
// s_barrier -> ds_read frags -> 32 MFMA (16x16x32).
// A: FOUR slots, slot(t)=t%4 (WAR-safe at issue distance 2).
// X: rolling 5-slot row buffer, slot(r,c) = (4c+r)%5; row3@c staged taps 1-2,
// rows 0-2 of c+1 at taps 3-8 (every write >= 1 full barrier after the last
// read of the slot's old content).
// NW tables FIFO-derived: c0 [2,4,4,5,6,7,7,7,7]; steady [6,6,6,7,7,7,7,7,7];
// tail [6,6,6,6,5,4,4,2,0]. LDS 72.6 KB -> 2 blocks/CU (8 waves, 2/SIMD);
// 112 arch + 128 acc = 240 unified <= 256 -> 2 waves/SIMD, no spill.
// ---------------------------------------------------------------------------
__global__ __launch_bounds__(256, 2)
void rotconv_mfma_kernel(const __hip_bfloat16* __restrict__ xb,
                         const __hip_bfloat16* __restrict__ rwb,
                         float* __restrict__ out) {
    const int tid  = threadIdx.x;
    const int lane = tid & 63;
    const int w    = tid >> 6;        // 0..3
    const int wm   = w >> 1;          // 0..1
    const int wn   = w & 1;           // 0..1  (owns output row y0+wn)
    const int q    = lane >> 4, lr = lane & 15;

    // bijective XCD swizzle (4096 % 8 == 0), m-major for A-panel L2 reuse
    const int bid = (blockIdx.x & 7) * 512 + (blockIdx.x >> 3);
    const int mt  = bid >> 8;         // 0..15
    const int nt  = bid & 255;        // 0..255
    const int b   = nt >> 6;          // 0..3
    const int y0  = (nt & 63) * 2;    // 0..126
    const int m0  = mt << 7;

    __shared__ __align__(16) __hip_bfloat16 xs[5 * ROWSZ];
    __shared__ __align__(16) __hip_bfloat16 As[4 * ABUF];

    // zero halo columns (colL = 0 and 129) of all 5 slots (stay zero forever)
    for (int j = tid; j < 5 * 64; j += 256) {
        int slot = j >> 6;
        int rem  = j & 63;
        int colL = (rem >> 5) ? 129 : 0;
        int ch   = rem & 31;
        xs[slot * ROWSZ + colL * 32 + ch] = __float2bfloat16(0.0f);
    }

    // ---- A read offset (single reg; rows step by 16 -> swizzle invariant) --
    const int arow_r = wm * 64 + lr;
    const int aOff0  = arow_r * 32 + 8 * (q ^ ((arow_r >> 1) & 3));
    // ---- B read offsets: colL = lr + kx (ni*16 -> imm; swizzle inv mod 16) -
    int bOff0[3];
    #pragma unroll
    for (int kx = 0; kx < 3; ++kx) {
        int colL = lr + kx;
        bOff0[kx] = colL * 32 + 8 * (q ^ ((colL >> 1) & 3));
    }

    // ---- A staging: wave w covers rows w*32..w*32+31 (2 g2l per wave) ----
    const int arow0 = w * 32 + (lane >> 2);
    const int arow1 = arow0 + 16;
    const int dstA0 = (w * 32) * 32;                    // wave-uniform
    const int dstA1 = (w * 32 + 16) * 32;
    const int voffA0 = (m0 + arow0) * (KTAPS * CIN) + 8 * ((lane & 3) ^ ((arow0 >> 1) & 3));
    const int voffA1 = (m0 + arow1) * (KTAPS * CIN) + 8 * ((lane & 3) ^ ((arow1 >> 1) & 3));

    // ---- X staging: 4 window rows x 2 col-parts/wave ----
    int rowOff[4];                                      // wave-uniform -> SGPR
    #pragma unroll
    for (int r = 0; r < 4; ++r) {
        int gy = y0 - 1 + r;
        int rowIdx = ((unsigned)gy < (unsigned)HH) ? (b * HH + gy) : (BB * HH);
        rowOff[r] = rowIdx * (WW * CIN);
    }
    const int gx0   = w * 16 + (lane >> 2);
    const int voffX = gx0 * CIN + 8 * ((lane & 3) ^ (((gx0 + 1) >> 1) & 3));
    const int dstXp0 = 32 + w * 512;                    // elem offset in slot
    const int dstXp1 = 32 + (w + 4) * 512;

    f32x4 acc[4][8];
    #pragma unroll
    for (int mi = 0; mi < 4; ++mi)
        #pragma unroll
        for (int ni = 0; ni < 8; ++ni) {
            f32x4 z = {0.f, 0.f, 0.f, 0.f};
            acc[mi][ni] = z;
        }

    __syncthreads();   // halo zeros visible

    // prologue: X rows r0..r3 -> slots 0..3 (chunk 0); A(0)->s0, A(1)->s1
    #pragma unroll
    for (int r = 0; r < 4; ++r) {
        g2l16(xs + r * ROWSZ + dstXp0, xb + rowOff[r] + voffX);
        g2l16(xs + r * ROWSZ + dstXp1, xb + rowOff[r] + voffX + 64 * CIN);
    }
    g2l16(As + dstA0, rwb + voffA0);
    g2l16(As + dstA1, rwb + voffA1);
    g2l16(As + ABUF + dstA0, rwb + voffA0 + CIN);
    g2l16(As + ABUF + dstA1, rwb + voffA1 + CIN);
    asm volatile("s_waitcnt vmcnt(0)" ::: "memory");
    __syncthreads();

#define WRAP5(v) ((v) >= 5 ? (v) - 5 : (v))

// ---- one tap (literal chunk C, tap P): issue A(t+2) into slot (C+P+2)&3
//      [+ one X row part] -> counted wait -> barrier -> ds_read A slot
//      (C+P)&3 + B row -> 32 MFMA in 2 half-clusters.
#define TAP(C, P, NW, DOA, DOX, XIDX, XSLOT, XOFF)                             \
  {                                                                            \
    if (DOA) {                                                                 \
      __hip_bfloat16* ab = As + (((C) + (P) + 2) & 3) * ABUF;                  \
      const int aofs = (((P) + 2) % 9) * CIN + ((((P) + 2) / 9) + (C)) * 32;   \
      g2l16(ab + dstA0, rwb + voffA0 + aofs);                                  \
      g2l16(ab + dstA1, rwb + voffA1 + aofs);                                  \
    }                                                                          \
    if (DOX) {                                                                 \
      g2l16(xs + (XSLOT) * ROWSZ + (((XIDX) & 1) ? dstXp1 : dstXp0),           \
            xb + rowOff[(XIDX) >> 1] + voffX + ((XIDX) & 1) * (64 * CIN)       \
               + (XOFF));                                                      \
    }                                                                          \
    asm volatile("s_waitcnt vmcnt(%0)" :: "i"(NW) : "memory");                 \
    asm volatile("s_barrier" ::: "memory");                                    \
    {                                                                          \
      const __hip_bfloat16* ar = As + (((C) + (P)) & 3) * ABUF + aOff0;        \
      const __hip_bfloat16* br =                                               \
          ((P) / 3 == 0 ? xrow0 : (P) / 3 == 1 ? xrow1 : xrow2)                \
          + bOff0[(P) % 3];                                                    \
      bf16x8 af[4];                                                            \
      _Pragma("unroll")                                                        \
      for (int mi = 0; mi < 4; ++mi) af[mi] = *(const bf16x8*)(ar + mi * 512); \
      _Pragma("unroll")                                                        \
      for (int h = 0; h < 2; ++h) {                                            \
        bf16x8 bv[4];                                                          \
        _Pragma("unroll")                                                      \
        for (int nj = 0; nj < 4; ++nj)                                         \
            bv[nj] = *(const bf16x8*)(br + (h * 4 + nj) * 512);                \
        __builtin_amdgcn_s_setprio(1);                                         \
        _Pragma("unroll")                                                      \
        for (int mi = 0; mi < 4; ++mi)                                         \
          _Pragma("unroll")                                                    \
          for (int nj = 0; nj < 4; ++nj)                                       \
            acc[mi][h * 4 + nj] = __builtin_amdgcn_mfma_f32_16x16x32_bf16(     \
                af[mi], bv[nj], acc[mi][h * 4 + nj], 0, 0, 0);                 \
        __builtin_amdgcn_s_setprio(0);                                         \
      }                                                                        \
    }                                                                          \
  }

#define CHUNK_HDR(C)                                                           \
    const int rbw = ((4 * (C)) % 5) + wn;                                      \
    const __hip_bfloat16* xrow0 = xs + WRAP5(rbw) * ROWSZ;                     \
    const __hip_bfloat16* xrow1 = xs + WRAP5(rbw + 1) * ROWSZ;                 \
    const __hip_bfloat16* xrow2 = xs + WRAP5(rbw + 2) * ROWSZ;

// steady chunk C=1..6: X row3@C at taps 1-2 (slot (4C+3)%5), rows 0-2 of C+1
// at taps 3-8 (slots (4C+4)%5, (4C)%5, (4C+1)%5). NW [6,6,6,7,7,7,7,7,7].
#define CHK_MID(C)                                                             \
  { CHUNK_HDR(C)                                                               \
    TAP(C, 0, 6, 1, 0, 0, 0, 0)                                                \
    TAP(C, 1, 6, 1, 1, 6, (4*(C)+3)%5, (C)*32)                                 \
    TAP(C, 2, 6, 1, 1, 7, (4*(C)+3)%5, (C)*32)                                 \
    TAP(C, 3, 7, 1, 1, 0, (4*(C)+4)%5, ((C)+1)*32)                             \
    TAP(C, 4, 7, 1, 1, 1, (4*(C)+4)%5, ((C)+1)*32)                             \
    TAP(C, 5, 7, 1, 1, 2, (4*(C))%5,   ((C)+1)*32)                             \
    TAP(C, 6, 7, 1, 1, 3, (4*(C))%5,   ((C)+1)*32)                             \
    TAP(C, 7, 7, 1, 1, 4, (4*(C)+1)%5, ((C)+1)*32)                             \
    TAP(C, 8, 7, 1, 1, 5, (4*(C)+1)%5, ((C)+1)*32)                             \
  }

    // ---- chunk 0: rows 0-3 prologue-staged; stage rows 0-2 of c1 at taps 3-8
    { CHUNK_HDR(0)
      TAP(0, 0, 2, 1, 0, 0, 0, 0)
      TAP(0, 1, 4, 1, 0, 0, 0, 0)
      TAP(0, 2, 4, 1, 0, 0, 0, 0)
      TAP(0, 3, 5, 1, 1, 0, 4, 32)
      TAP(0, 4, 6, 1, 1, 1, 4, 32)
      TAP(0, 5, 7, 1, 1, 2, 0, 32)
      TAP(0, 6, 7, 1, 1, 3, 0, 32)
      TAP(0, 7, 7, 1, 1, 4, 1, 32)
      TAP(0, 8, 7, 1, 1, 5, 1, 32)
    }

    CHK_MID(1) CHK_MID(2) CHK_MID(3) CHK_MID(4) CHK_MID(5) CHK_MID(6)

    // ---- tail chunk 7: row3@c7 at taps 1-2 (slot (31)%5=1); A while t+2<=71
    { CHUNK_HDR(7)
      TAP(7, 0, 6, 1, 0, 0, 0, 0)
      TAP(7, 1, 6, 1, 1, 6, 1, 224)
      TAP(7, 2, 6, 1, 1, 7, 1, 224)
      TAP(7, 3, 6, 1, 0, 0, 0, 0)
      TAP(7, 4, 5, 1, 0, 0, 0, 0)
      TAP(7, 5, 4, 1, 0, 0, 0, 0)
      TAP(7, 6, 4, 1, 0, 0, 0, 0)
      TAP(7, 7, 2, 0, 0, 0, 0, 0)
      TAP(7, 8, 0, 0, 0, 0, 0, 0)
    }

#undef TAP
#undef CHK_MID
#undef CHUNK_HDR
#undef WRAP5

    // epilogue: max over 8 rotations (4 regs + quarter-swap), write fp32
    const int oBase = (m0 + wm * 64) >> 3;
    const int yOut  = y0 + wn;
    #pragma unroll
    for (int mi = 0; mi < 4; ++mi) {
        #pragma unroll
        for (int ni = 0; ni < 8; ++ni) {
            f32x4 a4 = acc[mi][ni];
            float v = fmaxf(fmaxf(a4[0], a4[1]), fmaxf(a4[2], a4[3]));
            v = fmaxf(v, __shfl_xor(v, 16));
            if ((q & 1) == 0) {
                int o = oBase + mi * 2 + (q >> 1);
                int colc = ni * 16 + lr;
                out[(((size_t)(b * COUT + o)) * HH + yOut) * WW + colc] = v;
            }
        }
    }
}

// ===========================================================================
// Fallback fp32 path (round-0, known-correct) in case ws is too small.
// ===========================================================================
__global__ void rotate_weights_kernel(const float* __restrict__ w,
                                      float* __restrict__ rw,
                                      int r0, int rcount) {
    int idx = blockIdx.x * blockDim.x + threadIdx.x;
    int total = COUT * CIN * rcount;
    if (idx >= total) return;
    int rr = idx % rcount;
    int ii = (idx / rcount) % CIN;
    int oo = idx / (rcount * CIN);
    int r  = r0 + rr;
    float ang = 6.283185307179586f * (float)r / 8.0f;
    float cs = cosf(ang), sn = sinf(ang);
    const float* wp = w  + ((size_t)oo * CIN + ii) * 9;
    float*       op = rw + (((size_t)oo * CIN + ii) * rcount + rr) * 9;
    #pragma unroll
    for (int ky = 0; ky < 3; ++ky)
        #pragma unroll
        for (int kx = 0; kx < 3; ++kx) {
            float yg = (2.0f * ky + 1.0f) / 3.0f - 1.0f;
            float xg = (2.0f * kx + 1.0f) / 3.0f - 1.0f;
            float xsf = cs * xg - sn * yg;
            float ysf = sn * xg + cs * yg;
            float ix = ((xsf + 1.0f) * 3.0f - 1.0f) * 0.5f;
            float iy = ((ysf + 1.0f) * 3.0f - 1.0f) * 0.5f;
            float ix0f = floorf(ix), iy0f = floorf(iy);
            float wx1 = ix - ix0f,  wy1 = iy - iy0f;
            float wx0 = 1.0f - wx1, wy0 = 1.0f - wy1;
            int ix0 = (int)ix0f, iy0 = (int)iy0f;
            int ix1 = ix0 + 1,   iy1 = iy0 + 1;
            float acc = 0.0f;
            if (iy0 >= 0 && iy0 < 3 && ix0 >= 0 && ix0 < 3) acc += wp[iy0*3+ix0]*(wy0*wx0);
            if (iy0 >= 0 && iy0 < 3 && ix1 >= 0 && ix1 < 3) acc += wp[iy0*3+ix1]*(wy0*wx1);
            if (iy1 >= 0 && iy1 < 3 && ix0 >= 0 && ix0 < 3) acc += wp[iy1*3+ix0]*(wy1*wx0);
            if (iy1 >= 0 && iy1 < 3 && ix1 >= 0 && ix1 < 3) acc += wp[iy1*3+ix1]*(wy1*wx1);
            op[ky * 3 + kx] = acc;
        }
}

template <int RCOUNT>
__global__ __launch_bounds__(256)
void rotconv_max_kernel(const float* __restrict__ x,
                        const float* __restrict__ rw,
                        float* __restrict__ out,
                        int first) {
    const int tid = threadIdx.x;
    const int tx = tid & 15;
    const int ty = tid >> 4;
    const int x0 = blockIdx.x * 32;
    const int y0 = blockIdx.y * 32;
    const int o  = blockIdx.z % COUT;
    const int b  = blockIdx.z / COUT;
    __shared__ float xsm[34][36];
    float acc[RCOUNT][2][2];
    #pragma unroll
    for (int r = 0; r < RCOUNT; ++r)
        #pragma unroll
        for (int py = 0; py < 2; ++py)
            #pragma unroll
            for (int px = 0; px < 2; ++px) acc[r][py][px] = 0.0f;
    for (int i = 0; i < CIN; ++i) {
        __syncthreads();
        const float* xp = x + ((size_t)(b * CIN + i)) * (HH * WW);
        for (int idx = tid; idx < 34 * 34; idx += 256) {
            int row = idx / 34, col = idx - row * 34;
            int gy = y0 - 1 + row, gx = x0 - 1 + col;
            float v = 0.0f;
            if (gy >= 0 && gy < HH && gx >= 0 && gx < WW) v = xp[gy * WW + gx];
            xsm[row][col] = v;
        }
        __syncthreads();
        float xv[4][4];
        #pragma unroll
        for (int ry = 0; ry < 4; ++ry)
            #pragma unroll
            for (int cx = 0; cx < 4; ++cx) xv[ry][cx] = xsm[ty*2+ry][tx*2+cx];
        const float* wp = rw + ((size_t)(o * CIN + i)) * (RCOUNT * 9);
        #pragma unroll
        for (int r = 0; r < RCOUNT; ++r) {
            float wv[9];
            #pragma unroll
            for (int t2 = 0; t2 < 9; ++t2) wv[t2] = wp[r * 9 + t2];
            #pragma unroll
            for (int py = 0; py < 2; ++py)
                #pragma unroll
                for (int px = 0; px < 2; ++px) {
                    float a = acc[r][py][px];
                    #pragma unroll
                    for (int ky = 0; ky < 3; ++ky)
                        #pragma unroll
                        for (int kx = 0; kx < 3; ++kx)
                            a += xv[py+ky][px+kx] * wv[ky*3+kx];
                    acc[r][py][px] = a;
                }
        }
    }
    #pragma unroll
    for (int py = 0; py < 2; ++py)
        #pragma unroll
        for (int px = 0; px < 2; ++px) {
            float m = acc[0][py][px];
            #pragma unroll
            for (int r = 1; r < RCOUNT; ++r) m = fmaxf(m, acc[r][py][px]);
            int oy = y0 + ty * 2 + py;
            int ox = x0 + tx * 2 + px;
            float* op = out + (((size_t)(b * COUT + o)) * HH + oy) * WW + ox;
            if (first) *op = m;
            else       *op = fmaxf(*op, m);
        }
}

// ===========================================================================
extern "C" void kernel_launch(void* const* d_in, const int* in_sizes, int n_in,
                              void* d_out, int out_size, void* d_ws, size_t ws_size,
                              hipStream_t stream) {
    const float* x = (const float*)d_in[0];
    const float* w = (const float*)d_in[1];
    float* out = (float*)d_out;

    const size_t xbBytes = ((size_t)BB * HH * WW + WW) * CIN * sizeof(__hip_bfloat16); // +1 zero row
    const size_t rwBytes = (size_t)MTOT * KTAPS * CIN * sizeof(__hip_bfloat16);

    if (ws_size >= xbBytes + rwBytes) {
        __hip_bfloat16* xbuf = (__hip_bfloat16*)d_ws;
        __hip_bfloat16* rwb  = (__hip_bfloat16*)((char*)d_ws + xbBytes);

        to_nhwc_bf16<<<dim3((HH * WW) / 32, CIN / 32, BB), 256, 0, stream>>>(x, xbuf);
        zero_guard_row<<<(WW * CIN) / 256, 256, 0, stream>>>(xbuf);
        rotate_weights_bf16<<<MTOT, 256, 0, stream>>>(w, rwb);
        rotconv_mfma_kernel<<<4096, 256, 0, stream>>>(xbuf, rwb, out);
        return;
    }

    // ---- fallback fp32 path ----
    float* rw = (float*)d_ws;
    int chunk = 8;
    while (chunk > 1 && (size_t)COUT * CIN * chunk * 9 * sizeof(float) > ws_size)
        chunk >>= 1;
    int first = 1;
    for (int r0 = 0; r0 < R_TOTAL; r0 += chunk) {
        int rc = chunk;
        int total = COUT * CIN * rc;
        rotate_weights_kernel<<<(total + 255) / 256, 256, 0, stream>>>(w, rw, r0, rc);
        dim3 grid(WW / 32, HH / 32, BB * COUT);
        switch (rc) {
            case 8: rotconv_max_kernel<8><<<grid, 256, 0, stream>>>(x, rw, out, first); break;
            case 4: rotconv_max_kernel<4><<<grid, 256, 0, stream>>>(x, rw, out, first); break;
            case 2: rotconv_max_kernel<2><<<grid, 256, 0, stream>>>(x, rw, out, first); break;
            default: rotconv_max_kernel<1><<<grid, 256, 0, stream>>>(x, rw, out, first); break;
        }
        first = 0;
    }
}